// Round 7
// baseline (168.681 us; speedup 1.0000x reference)
//
#include <hip/hip_runtime.h>
#include <math.h>
#include <limits.h>

#define D 128
#define NSUBJ 16
#define MAXN 640        // max rows/subject: 512 mean + ~6 sigma
#define MARGIN 0.8f
#define EPS 1e-6f
#define TI 16           // i-rows per block stripe (one MFMA row-tile)
#define NSTRIPE 32      // stripes per subject
#define NBLK (NSUBJ * NSTRIPE)   // 512 blocks = 2/CU, 8 waves/CU

typedef __attribute__((ext_vector_type(8))) short bf16x8;
typedef __attribute__((ext_vector_type(4))) float f32x4;

static __device__ __forceinline__ short f2bf(float f) {
    union { float f; unsigned u; } v; v.f = f;
    unsigned r = v.u + 0x7FFF + ((v.u >> 16) & 1);   // RNE
    return (short)(r >> 16);
}
static __device__ __forceinline__ bf16x8 cvt8(float4 a, float4 b) {
    bf16x8 p;
    p[0] = f2bf(a.x); p[1] = f2bf(a.y); p[2] = f2bf(a.z); p[3] = f2bf(a.w);
    p[4] = f2bf(b.x); p[5] = f2bf(b.y); p[6] = f2bf(b.z); p[7] = f2bf(b.w);
    return p;
}

// Single fused kernel: per-block subject compaction (ballot scan) -> LDS meta
// -> MFMA Gram + hardest-pos/neg selection -> exact fp32 distances -> ticket
// finalize. No intermediate global arrays; fp32->bf16 at fragment-load time.
__global__ __launch_bounds__(256, 2) void triplet_kernel(
        const float* __restrict__ emb, const int* __restrict__ labels,
        const int* __restrict__ sbj,
        float* __restrict__ loss_sum, int* __restrict__ valid_cnt,
        int* __restrict__ done, float* __restrict__ out, int B) {
    const int bid = blockIdx.x, t = threadIdx.x;
    const int s = bid & 15;              // subject; blocks of s land on XCD s%8
    const int stripe = bid >> 4;         // 0..31
    const int lane = t & 63, w = t >> 6, c = lane & 15, q = lane >> 4;

    __shared__ int   lst[MAXN];          // original row indices, ascending
    __shared__ int   lab[MAXN];
    __shared__ float lsq[MAXN];
    __shared__ int   s_n;
    __shared__ float svP[TI][4]; __shared__ int siP[TI][4];
    __shared__ float svN[TI][4]; __shared__ int siN[TI][4];
    __shared__ int   selP[TI], selN[TI];
    __shared__ float perRow[TI]; __shared__ int validRow[TI];

    // ---- phase 0 (wave 0): ordered compaction of this subject's rows ----
    if (w == 0) {
        int base = 0;
        for (int k0 = 0; k0 < B; k0 += 64) {
            int k = k0 + lane;
            bool m = (sbj[k] == s);
            unsigned long long mask = __ballot(m);
            int idx = base + __popcll(mask & ((1ull << lane) - 1));
            if (m && idx < MAXN) lst[idx] = k;
            base += __popcll(mask);
        }
        if (lane == 0) s_n = min(base, MAXN);
    }
    __syncthreads();
    const int n = s_n;

    // ---- phase 1: labels + squared norms into LDS (16 threads per row) ----
    for (int r0 = 0; r0 < n; r0 += 16) {
        int row = r0 + (t >> 4), u = t & 15;
        float ssq = 0.f; int g = 0;
        if (row < n) {
            g = lst[row];
            const float4* rp = (const float4*)(emb + (size_t)g * D);
            float4 a = rp[u * 2], b = rp[u * 2 + 1];
            ssq = fmaf(a.x, a.x, ssq); ssq = fmaf(a.y, a.y, ssq);
            ssq = fmaf(a.z, a.z, ssq); ssq = fmaf(a.w, a.w, ssq);
            ssq = fmaf(b.x, b.x, ssq); ssq = fmaf(b.y, b.y, ssq);
            ssq = fmaf(b.z, b.z, ssq); ssq = fmaf(b.w, b.w, ssq);
        }
#pragma unroll
        for (int off = 8; off > 0; off >>= 1) ssq += __shfl_down(ssq, off, 16);
        if (row < n && u == 0) { lsq[row] = ssq; lab[row] = labels[g]; }
    }
    __syncthreads();

    float blockSum = 0.f; int blockCnt = 0;

    // ---- phase 2: stripes of 16 i-rows; waves split the j-range ----
    for (int i0 = stripe * TI; i0 < n; i0 += NSTRIPE * TI) {
        const int nrows = min(TI, n - i0);
        __syncthreads();                  // selection scratch reusable

        // A fragments: fp32 gather + cvt, rows shared by all 4 waves
        bf16x8 afr[4];
        {
            int ga = lst[i0 + min(c, nrows - 1)];
            const float4* ap = (const float4*)(emb + (size_t)ga * D);
#pragma unroll
            for (int st = 0; st < 4; ++st)
                afr[st] = cvt8(ap[st * 8 + q * 2], ap[st * 8 + q * 2 + 1]);
        }
        int li[4], gI[4];
#pragma unroll
        for (int r = 0; r < 4; ++r) {
            int row = i0 + q * 4 + r;
            if (row < n) { li[r] = lab[row]; gI[r] = lst[row]; }
            else         { li[r] = INT_MIN; gI[r] = -1; }
        }

        float vP[4], vN[4]; int iP[4], iN[4];
#pragma unroll
        for (int r = 0; r < 4; ++r) {
            vP[r] = -INFINITY; iP[r] = -1;
            vN[r] =  INFINITY; iN[r] = -1;
        }

        // wave w handles 16-col tiles jt = w, w+4, w+8, ...  (1-ahead pipeline)
        const int nt = (n + 15) >> 4;
        float4 raw[8]; int pj = -1, plb = INT_MIN; float psq = 0.f;
        if (w < nt) {
            int col = w * 16 + c, cl = min(col, n - 1);
            int g = lst[cl];
            const float4* rp = (const float4*)(emb + (size_t)g * D);
#pragma unroll
            for (int st = 0; st < 4; ++st) {
                raw[2 * st]     = rp[st * 8 + q * 2];
                raw[2 * st + 1] = rp[st * 8 + q * 2 + 1];
            }
            pj = (col < n) ? g : -1;
            plb = lab[cl]; psq = lsq[cl];
        }
        for (int jt = w; jt < nt; jt += 4) {
            bf16x8 bfr[4];
#pragma unroll
            for (int st = 0; st < 4; ++st) bfr[st] = cvt8(raw[2 * st], raw[2 * st + 1]);
            int mj = pj, ml = plb; float ms = psq;
            int jn = jt + 4;
            if (jn < nt) {                // prefetch next tile while MFMA runs
                int col = jn * 16 + c, cl = min(col, n - 1);
                int g = lst[cl];
                const float4* rp = (const float4*)(emb + (size_t)g * D);
#pragma unroll
                for (int st = 0; st < 4; ++st) {
                    raw[2 * st]     = rp[st * 8 + q * 2];
                    raw[2 * st + 1] = rp[st * 8 + q * 2 + 1];
                }
                pj = (col < n) ? g : -1;
                plb = lab[cl]; psq = lsq[cl];
            }
            f32x4 acc = {0.f, 0.f, 0.f, 0.f};
            acc = __builtin_amdgcn_mfma_f32_16x16x32_bf16(afr[0], bfr[0], acc, 0, 0, 0);
            acc = __builtin_amdgcn_mfma_f32_16x16x32_bf16(afr[1], bfr[1], acc, 0, 0, 0);
            acc = __builtin_amdgcn_mfma_f32_16x16x32_bf16(afr[2], bfr[2], acc, 0, 0, 0);
            acc = __builtin_amdgcn_mfma_f32_16x16x32_bf16(afr[3], bfr[3], acc, 0, 0, 0);
            // lane holds dot(row i0+q*4+r, col jt*16+c); d2-rel = ms - 2*dot
            if (mj >= 0) {
#pragma unroll
                for (int r = 0; r < 4; ++r) {
                    float v = fmaf(-2.f, acc[r], ms);
                    if (ml == li[r]) {
                        if (mj != gI[r] && (v > vP[r] ||
                            (v == vP[r] && (unsigned)mj < (unsigned)iP[r]))) {
                            vP[r] = v; iP[r] = mj;
                        }
                    } else if (v < vN[r] ||
                               (v == vN[r] && (unsigned)mj < (unsigned)iN[r])) {
                        vN[r] = v; iN[r] = mj;
                    }
                }
            }
        }

        // reduce across the 16 col-lanes (tie-break: smallest original index)
#pragma unroll
        for (int off = 8; off > 0; off >>= 1) {
#pragma unroll
            for (int r = 0; r < 4; ++r) {
                float ov = __shfl_down(vP[r], off, 16);
                int   oi = __shfl_down(iP[r], off, 16);
                if (ov > vP[r] || (ov == vP[r] && (unsigned)oi < (unsigned)iP[r])) {
                    vP[r] = ov; iP[r] = oi;
                }
                float on = __shfl_down(vN[r], off, 16);
                int   oj = __shfl_down(iN[r], off, 16);
                if (on < vN[r] || (on == vN[r] && (unsigned)oj < (unsigned)iN[r])) {
                    vN[r] = on; iN[r] = oj;
                }
            }
        }
        if (c == 0) {
#pragma unroll
            for (int r = 0; r < 4; ++r) {
                int row = q * 4 + r;
                svP[row][w] = vP[r]; siP[row][w] = iP[r];
                svN[row][w] = vN[r]; siN[row][w] = iN[r];
            }
        }
        __syncthreads();
        if (t < TI) {
            float bp = svP[t][0]; int ip = siP[t][0];
            float bn = svN[t][0]; int in_ = siN[t][0];
#pragma unroll
            for (int ww = 1; ww < 4; ++ww) {
                float o = svP[t][ww]; int oi = siP[t][ww];
                if (o > bp || (o == bp && (unsigned)oi < (unsigned)ip)) { bp = o; ip = oi; }
                float on = svN[t][ww]; int oj = siN[t][ww];
                if (on < bn || (on == bn && (unsigned)oj < (unsigned)in_)) { bn = on; in_ = oj; }
            }
            selP[t] = ip; selN[t] = in_;
        }
        __syncthreads();

        // exact fp32 distances: 16 threads per row, 2 float4 each
        {
            int row = t >> 4, u = t & 15;
            int p = selP[row], nn = selN[row];
            bool valid = (row < nrows) && (p >= 0) && (nn >= 0);
            int g = valid ? lst[i0 + row] : 0;
            float sump = 0.f, sumn = 0.f;
            if (valid) {
                const float4* ai = (const float4*)(emb + (size_t)g * D);
                const float4* ep = (const float4*)(emb + (size_t)p * D);
                const float4* en = (const float4*)(emb + (size_t)nn * D);
#pragma unroll
                for (int z = 0; z < 2; ++z) {
                    int c4 = u * 2 + z;
                    float4 x = ai[c4], vp = ep[c4], vn = en[c4];
                    float d;
                    d = x.x - vp.x + EPS; sump = fmaf(d, d, sump);
                    d = x.y - vp.y + EPS; sump = fmaf(d, d, sump);
                    d = x.z - vp.z + EPS; sump = fmaf(d, d, sump);
                    d = x.w - vp.w + EPS; sump = fmaf(d, d, sump);
                    d = x.x - vn.x + EPS; sumn = fmaf(d, d, sumn);
                    d = x.y - vn.y + EPS; sumn = fmaf(d, d, sumn);
                    d = x.z - vn.z + EPS; sumn = fmaf(d, d, sumn);
                    d = x.w - vn.w + EPS; sumn = fmaf(d, d, sumn);
                }
            }
#pragma unroll
            for (int off = 8; off > 0; off >>= 1) {
                sump += __shfl_down(sump, off, 16);
                sumn += __shfl_down(sumn, off, 16);
            }
            if (u == 0) {
                perRow[row]   = valid ? fmaxf(sqrtf(sump) - sqrtf(sumn) + MARGIN, 0.f) : 0.f;
                validRow[row] = valid ? 1 : 0;
            }
        }
        __syncthreads();
        if (t == 0) {
#pragma unroll
            for (int r = 0; r < TI; ++r) { blockSum += perRow[r]; blockCnt += validRow[r]; }
        }
    }

    // ---- ticket finalize: last block writes the mean ----
    if (t == 0) {
        if (blockCnt > 0) {
            atomicAdd(loss_sum, blockSum);
            atomicAdd(valid_cnt, blockCnt);
        }
        __threadfence();
        int ticket = atomicAdd(done, 1);
        if (ticket == NBLK - 1) {
            float sum = atomicAdd(loss_sum, 0.0f);
            int   cnt = atomicAdd(valid_cnt, 0);
            out[0] = (cnt > 0) ? (sum / (float)cnt) : 0.0f;
        }
    }
}

extern "C" void kernel_launch(void* const* d_in, const int* in_sizes, int n_in,
                              void* d_out, int out_size, void* d_ws, size_t ws_size,
                              hipStream_t stream) {
    const float* emb    = (const float*)d_in[0];
    const int*   labels = (const int*)d_in[1];
    const int*   sbj    = (const int*)d_in[2];
    float*       out    = (float*)d_out;
    int B = in_sizes[1];   // 8192

    // Workspace: [64,68) float loss_sum  [72,76) int valid_cnt  [80,84) int done
    char*  ws        = (char*)d_ws;
    float* loss_sum  = (float*)(ws + 64);
    int*   valid_cnt = (int*)(ws + 72);
    int*   done      = (int*)(ws + 80);

    hipMemsetAsync(ws, 0, 128, stream);
    triplet_kernel<<<NBLK, 256, 0, stream>>>(emb, labels, sbj,
                                             loss_sum, valid_cnt, done, out, B);
}